// Round 15
// baseline (343.196 us; speedup 1.0000x reference)
//
#include <hip/hip_runtime.h>
#include <math.h>

#define BATCH 4
#define CH    256
#define NSP   4096          // 16*16*16
#define NGRP  32
#define EPS_GN 1e-5f
#define LOG2E 1.44269504088896f
#define M0    115.0f        // fixed softmax base (exp2 domain)

typedef _Float16 f16;
typedef f16 f16x8 __attribute__((ext_vector_type(8)));
typedef f16 f16x4 __attribute__((ext_vector_type(4)));
typedef short s16x8 __attribute__((ext_vector_type(8)));   // bf16 frags
typedef float f32x4 __attribute__((ext_vector_type(4)));
typedef unsigned short u16;

#define QK_MFMA(a,b,c) __builtin_amdgcn_mfma_f32_16x16x32_f16(a,b,c,0,0,0)
#define PV_MFMA(a,b,c) __builtin_amdgcn_mfma_f32_16x16x32_bf16(a,b,c,0,0,0)

__device__ __forceinline__ float fexp2(float x) {
    float r; asm("v_exp_f32 %0, %1" : "=v"(r) : "v"(x)); return r;
}
__device__ __forceinline__ unsigned cvtpk_bf16(float lo, float hi) {
    unsigned r; asm("v_cvt_pk_bf16_f32 %0, %1, %2" : "=v"(r) : "v"(lo), "v"(hi)); return r;
}
__device__ __forceinline__ u16 f2bf(float x) {      // RTNE float->bf16
    unsigned u = __float_as_uint(x);
    return (u16)((u + 0x7fffu + ((u >> 16) & 1u)) >> 16);
}
#define GLOAD_LDS(gsrc, ldst) __builtin_amdgcn_global_load_lds( \
    (const __attribute__((address_space(1))) unsigned int*)(gsrc), \
    (__attribute__((address_space(3))) unsigned int*)(ldst), 16, 0, 0)

#define VM_BARRIER() do { \
    asm volatile("s_waitcnt vmcnt(0)" ::: "memory"); \
    __builtin_amdgcn_s_barrier(); \
    __builtin_amdgcn_sched_barrier(0); } while (0)

// ---------------------------------------------------------------------------
// prep: weights fp32 -> f16, layout [4][256][256] (wq*LOG2E, wk, wv, wo)
__global__ __launch_bounds__(256) void prep_w_kernel(
    const float* __restrict__ wq, const float* __restrict__ wk,
    const float* __restrict__ wv, const float* __restrict__ wo,
    f16* __restrict__ w16)
{
    const int i = (blockIdx.x * 256 + threadIdx.x) * 4;   // grid 256 -> 262144
    const float* src = (i < 65536) ? wq : (i < 131072) ? wk : (i < 196608) ? wv : wo;
    const float sc = (i < 65536) ? LOG2E : 1.f;           // fold softmax log2e into wq
    const float4 v = *(const float4*)&src[i & 65535];
    f16x4 o = { (f16)(v.x*sc), (f16)(v.y*sc), (f16)(v.z*sc), (f16)(v.w*sc) };
    *(f16x4*)&w16[i] = o;
}

// ---------------------------------------------------------------------------
// Fused QKV projection with in-LDS transpose: one block = 32 n x 256 o x 3 p.
// Reads x [B][C][N] fp32 directly; transposes the 32n x 256c tile into LDS
// f16 (XOR-swizzled), then 3 GEMMs vs prescaled W.
// q,k: [B][N][C] f16 (q scaled via prescaled wq); v: [B][C][N] bf16.
// grid (N/32, B), block 256 (4 waves; wave w -> o slice w*64..+64).
__global__ __launch_bounds__(256, 2) void qkv_kernel(
    const float* __restrict__ x, const f16* __restrict__ w16,
    const float* __restrict__ bq, const float* __restrict__ bk,
    const float* __restrict__ bv,
    f16* __restrict__ q16, f16* __restrict__ k16, u16* __restrict__ vt16)
{
    __shared__ __align__(16) char Xls[16384];   // [32 n][256 c] f16, swz
    const int b = blockIdx.y, n0 = blockIdx.x * 32;
    const int t = threadIdx.x, w = t >> 6, lane = t & 63;
    const int m = lane & 15, q4 = lane >> 4;

    {   // transpose-stage: thread (n = t&31) loads 4 floats per c-quad, packs
        const float* xb = x + (size_t)b*CH*NSP + n0;
        const int n = t & 31;
        #pragma unroll
        for (int p8 = 0; p8 < 8; ++p8) {
            const int c = ((t >> 5) + p8*8) * 4;
            f16x4 o4;
            #pragma unroll
            for (int j = 0; j < 4; ++j)
                o4[j] = (f16)xb[(size_t)(c + j)*NSP + n];
            *(f16x4*)(Xls + n*512 + ((c*2) ^ ((n & 7) << 4))) = o4;
        }
    }
    __syncthreads();

    #pragma unroll 1
    for (int p = 0; p < 3; ++p) {
        const f16* __restrict__ W = w16 + p*65536;
        f32x4 acc[4][2] = {};
        #pragma unroll
        for (int kc = 0; kc < 8; ++kc) {
            s16x8 bf[2];   // raw 16B type for f16 data
            #pragma unroll
            for (int nf = 0; nf < 2; ++nf) {
                const int row = nf*16 + m;
                bf[nf] = *(const s16x8*)(Xls + row*512 +
                             ((kc*64 + q4*16) ^ ((row & 7) << 4)));
            }
            #pragma unroll
            for (int ar = 0; ar < 4; ++ar) {
                const f16x8 af = *(const f16x8*)(W + (size_t)(w*64 + ar*16 + m)*CH
                                                 + kc*32 + q4*8);
                acc[ar][0] = QK_MFMA(af, *(const f16x8*)&bf[0], acc[ar][0]);
                acc[ar][1] = QK_MFMA(af, *(const f16x8*)&bf[1], acc[ar][1]);
            }
        }
        if (p < 2) {
            const float* bias = (p == 0) ? bq : bk;
            const float bsc = (p == 0) ? LOG2E : 1.f;
            f16* out = (p == 0) ? q16 : k16;
            #pragma unroll
            for (int ar = 0; ar < 4; ++ar) {
                const int ob = w*64 + ar*16 + q4*4;
                const float4 bb = *(const float4*)&bias[ob];
                #pragma unroll
                for (int nf = 0; nf < 2; ++nf) {
                    const int n = n0 + nf*16 + m;
                    f16x4 o4 = { (f16)(acc[ar][nf][0] + bb.x*bsc),
                                 (f16)(acc[ar][nf][1] + bb.y*bsc),
                                 (f16)(acc[ar][nf][2] + bb.z*bsc),
                                 (f16)(acc[ar][nf][3] + bb.w*bsc) };
                    *(f16x4*)(out + ((size_t)(b*NSP) + n)*CH + ob) = o4;
                }
            }
        } else {
            #pragma unroll
            for (int ar = 0; ar < 4; ++ar) {
                const int ob = w*64 + ar*16 + q4*4;
                const float4 bb = *(const float4*)&bv[ob];
                const float br[4] = {bb.x, bb.y, bb.z, bb.w};
                #pragma unroll
                for (int nf = 0; nf < 2; ++nf) {
                    const int n = n0 + nf*16 + m;
                    #pragma unroll
                    for (int r = 0; r < 4; ++r)
                        vt16[((size_t)(b*CH) + ob + r)*NSP + n] =
                            f2bf(acc[ar][nf][r] + br[r]);
                }
            }
        }
    }
}

// ---------------------------------------------------------------------------
// Flash attention: P fully in-register (no P-LDS roundtrip, no mid barrier).
// Wave w owns 16 q-rows (Q regs = 32 VGPR); QK = mfma(K_lds, Q) -> lane
// (m,q4) holds P[16 keys: kg*16+q4*4+r][qrow w*16+m].  Fragment re-map
// 4-key/lane -> 8-key/lane for PV via 8 __shfl + 4 select per 32-key chunk.
// PV = mfma(V_global, P_reg) -> lane-local H rows + lane-local l.
// K staged in shared LDS dbuf (global_load_lds, XOR-swz); 1 barrier/tile.
// q,k: [B][N][C] f16 (q pre-scaled); vt: [B][C][N] bf16.
// Outputs hk[2][B][N][C] f16 (per-half normalized) + lpart[2][B*N] f32.
// grid 512 = (b,ks via bid&7) x qblk(bid>>3); block 256 (4 waves), 64 q-rows.
__global__ __launch_bounds__(256)
__attribute__((amdgpu_waves_per_eu(2, 2)))
void attn_kernel(
    const f16* __restrict__ qg, const f16* __restrict__ kg,
    const u16* __restrict__ vtg, f16* __restrict__ hkg, float* __restrict__ lpart)
{
    __shared__ __align__(16) char Kls[2][32768];  // [64 keys][256c] f16, swz

    const int t = threadIdx.x, w = t >> 6, lane = t & 63;
    const int m = lane & 15, q4 = lane >> 4;
    const int swm = (m & 7) << 4;
    const int bid = blockIdx.x;
    const int b   = (bid & 7) >> 1;     // XCD-pinned (b,ks): K/V half = 2MB/L2
    const int ks  = bid & 1;
    const int qn0 = (bid >> 3) * 64;
    const int k00 = ks * 2048;

    // Q frags (B-operand): wave's 16 rows x 256 ch = 32 VGPR
    f16x8 qa[8];
    #pragma unroll
    for (int kc = 0; kc < 8; ++kc)
        qa[kc] = *(const f16x8*)(qg + ((size_t)(b*NSP) + qn0 + w*16 + m)*CH
                                 + kc*32 + q4*8);

    const char* kgb = (const char*)(kg + ((size_t)(b*NSP) + k00)*CH);
    // V (A-operand): lane (m,q4): V[ch=cf*16+m][key base + q4*8 .. +8] 16B
    const u16* vb_ = vtg + ((size_t)(b*CH) + m)*NSP + k00 + q4*8;

    auto stageK = [&](int buf, int tt) {
        const char* kgt = kgb + (size_t)tt * 64 * 512;
        char* dst = Kls[buf];
        #pragma unroll
        for (int i = 0; i < 8; ++i) {
            const int flat = i*4096 + t*16;
            const int key  = flat >> 9;
            const int off  = flat & 511;
            GLOAD_LDS(kgt + key*512 + (off ^ ((key & 7) << 4)), dst + flat);
        }
    };

    f32x4 acc[16] = {};                 // H^T[ch=cf*16+q4*4+r][qrow w*16+m]
    float lsum = 0.f;

    // shfl sources for the 4->8 key/lane re-map
    const int s0 = m + ((q4 & 1) << 5);        // lanes (m, (2q4)&3)
    const int s1 = m + 16 + ((q4 & 1) << 5);   // lanes (m, (2q4+1)&3)
    const bool lo = (q4 < 2);

    stageK(0, 0);

    #pragma unroll 1
    for (int tt = 0; tt < 32; ++tt) {
        const int buf = tt & 1;
        VM_BARRIER();                   // K(tt) landed
        if (tt < 31) stageK(buf ^ 1, tt + 1);

        const char* Kb = Kls[buf];
        #pragma unroll
        for (int kg2 = 0; kg2 < 2; ++kg2) {
            // V chunk loads first (latency hides under QK)
            s16x8 vf[16];
            #pragma unroll
            for (int cf = 0; cf < 16; ++cf)
                vf[cf] = *(const s16x8*)(vb_ + (size_t)(cf*16)*NSP
                                          + tt*64 + kg2*32);
            // ---- QK: 2 key-blocks (kg2*2, kg2*2+1) x own 16 rows ----
            f32x4 s[2] = {};
            __builtin_amdgcn_s_setprio(1);
            #pragma unroll
            for (int kc = 0; kc < 8; ++kc) {
                #pragma unroll
                for (int kk = 0; kk < 2; ++kk) {
                    const int key = (kg2*2 + kk)*16 + m;   // key&7 == m&7
                    const f16x8 kb = *(const f16x8*)(Kb + key*512 +
                                         ((kc*64 + q4*16) ^ swm));
                    s[kk] = QK_MFMA(kb, qa[kc], s[kk]);
                }
            }
            __builtin_amdgcn_s_setprio(0);

            // ---- exp (fixed base) -> bf16 pairs (keys q4*4+{0,1},{2,3}) ----
            unsigned pk0[2], pk1[2];
            #pragma unroll
            for (int kk = 0; kk < 2; ++kk) {
                const float p0 = fexp2(s[kk][0] - M0), p1 = fexp2(s[kk][1] - M0);
                const float p2 = fexp2(s[kk][2] - M0), p3 = fexp2(s[kk][3] - M0);
                lsum += (p0 + p1) + (p2 + p3);
                pk0[kk] = cvtpk_bf16(p0, p1);
                pk1[kk] = cvtpk_bf16(p2, p3);
            }

            // ---- re-map 4 keys/lane -> 8 keys/lane (B-operand pa) ----
            int4 pa;
            {
                const unsigned a0 = __shfl(pk0[0], s0), b0 = __shfl(pk0[1], s0);
                const unsigned a1 = __shfl(pk1[0], s0), b1 = __shfl(pk1[1], s0);
                const unsigned a2 = __shfl(pk0[0], s1), b2 = __shfl(pk0[1], s1);
                const unsigned a3 = __shfl(pk1[0], s1), b3 = __shfl(pk1[1], s1);
                pa.x = lo ? (int)a0 : (int)b0;
                pa.y = lo ? (int)a1 : (int)b1;
                pa.z = lo ? (int)a2 : (int)b2;
                pa.w = lo ? (int)a3 : (int)b3;
            }
            const s16x8 paf = *(const s16x8*)&pa;

            // ---- PV: H^T[ch][qrow] += V[ch][32 keys] . P[32 keys][qrow] ----
            __builtin_amdgcn_s_setprio(1);
            #pragma unroll
            for (int cf = 0; cf < 16; ++cf)
                acc[cf] = PV_MFMA(vf[cf], paf, acc[cf]);
            __builtin_amdgcn_s_setprio(0);
        }
    }

    // ---- epilogue: lane-local l (reduce over q4 lanes), normalize, store ----
    lsum += __shfl_xor(lsum, 16);
    lsum += __shfl_xor(lsum, 32);
    const float linv = 1.f / lsum;
    f16* hb = hkg + (size_t)ks*4194304
              + ((size_t)(b*NSP) + qn0 + w*16 + m)*CH;
    #pragma unroll
    for (int cf = 0; cf < 16; ++cf) {
        f16x4 o4 = { (f16)(acc[cf][0] * linv), (f16)(acc[cf][1] * linv),
                     (f16)(acc[cf][2] * linv), (f16)(acc[cf][3] * linv) };
        *(f16x4*)(hb + cf*16 + q4*4) = o4;
    }
    if (q4 == 0)
        lpart[ks*16384 + b*4096 + qn0 + w*16 + m] = lsum;
}

// ---------------------------------------------------------------------------
// Output projection with fused combine: one block = 32 n x 256 o.
// Stages h = (hk0*l0 + hk1*l1)/(l0+l1) into LDS, then GEMM vs wo16,
// adds residual x, writes y fp32 (= d_out), accumulates group stats.
// grid (N/32, B), block 256 (wave w -> o slice w*64..+64).
__global__ __launch_bounds__(256, 2) void oproj_kernel(
    const f16* __restrict__ hk, const float* __restrict__ lpart,
    const f16* __restrict__ wo16, const float* __restrict__ bo,
    const float* __restrict__ x, float* __restrict__ y, float* __restrict__ stats)
{
    __shared__ __align__(16) char Hls[16384];   // [32 n][256 c] f16, swz
    const int b = blockIdx.y, n0 = blockIdx.x * 32;
    const int t = threadIdx.x, w = t >> 6, lane = t & 63;
    const int m = lane & 15, q4 = lane >> 4;

    {   // stage combined h: 4 chunks of 16B per thread
        #pragma unroll
        for (int i = 0; i < 4; ++i) {
            const int flat = i*4096 + t*16;
            const int n = flat >> 9, off = flat & 511;
            const int nl = b*NSP + n0 + n;
            const float l0 = lpart[nl], l1 = lpart[16384 + nl];
            const float inv = 1.f / (l0 + l1);
            const float w0 = l0 * inv, w1 = l1 * inv;
            const f16x8 a = *(const f16x8*)(hk + (size_t)nl*CH + (off >> 1));
            const f16x8 c = *(const f16x8*)(hk + 4194304 + (size_t)nl*CH + (off >> 1));
            f16x8 o;
            #pragma unroll
            for (int j = 0; j < 8; ++j)
                o[j] = (f16)((float)a[j]*w0 + (float)c[j]*w1);
            *(f16x8*)(Hls + n*512 + (off ^ ((n & 7) << 4))) = o;
        }
    }
    __syncthreads();

    f32x4 acc[4][2] = {};
    #pragma unroll
    for (int kc = 0; kc < 8; ++kc) {
        s16x8 bf[2];
        #pragma unroll
        for (int nf = 0; nf < 2; ++nf) {
            const int row = nf*16 + m;
            bf[nf] = *(const s16x8*)(Hls + row*512 +
                         ((kc*64 + q4*16) ^ ((row & 7) << 4)));
        }
        #pragma unroll
        for (int ar = 0; ar < 4; ++ar) {
            const f16x8 af = *(const f16x8*)(wo16 + (size_t)(w*64 + ar*16 + m)*CH
                                             + kc*32 + q4*8);
            acc[ar][0] = QK_MFMA(af, *(const f16x8*)&bf[0], acc[ar][0]);
            acc[ar][1] = QK_MFMA(af, *(const f16x8*)&bf[1], acc[ar][1]);
        }
    }

    #pragma unroll
    for (int ar = 0; ar < 4; ++ar) {
        const int ob = w*64 + ar*16 + q4*4;
        const float4 bb = *(const float4*)&bo[ob];
        const float br[4] = {bb.x, bb.y, bb.z, bb.w};
        float s4 = 0.f, sq4 = 0.f;
        #pragma unroll
        for (int nf = 0; nf < 2; ++nf) {
            const int n = n0 + nf*16 + m;
            #pragma unroll
            for (int r = 0; r < 4; ++r) {
                const size_t idx = ((size_t)(b*CH + ob + r))*NSP + n;
                const float yv = acc[ar][nf][r] + br[r] + x[idx];
                y[idx] = yv;
                s4 += yv; sq4 += yv*yv;
            }
        }
        #pragma unroll
        for (int off = 1; off <= 16; off <<= 1) {
            s4  += __shfl_xor(s4, off);
            sq4 += __shfl_xor(sq4, off);
        }
        if ((lane & 31) == 0) {
            const int g = w*8 + ar*2 + (lane >> 5);
            atomicAdd(&stats[((size_t)(b*NGRP + g))*2 + 0], s4);
            atomicAdd(&stats[((size_t)(b*NGRP + g))*2 + 1], sq4);
        }
    }
}

// ---------------------------------------------------------------------------
// GroupNorm finalize + swish, in-place on y (= d_out).  grid (4, B*G).
__global__ __launch_bounds__(256) void gn_swish_kernel(
    float* __restrict__ y, const float* __restrict__ stats,
    const float* __restrict__ gamma, const float* __restrict__ beta)
{
    const int bg = blockIdx.y, quarter = blockIdx.x;
    const int b = bg >> 5, g = bg & 31;
    const float s  = stats[bg*2 + 0];
    const float sq = stats[bg*2 + 1];
    const float inv_n = 1.f / 32768.f;
    const float mu  = s * inv_n;
    const float var = sq * inv_n - mu*mu;
    const float rs  = rsqrtf(var + EPS_GN);
    float* __restrict__ base = y + ((size_t)b*CH + g*8)*NSP + quarter*8192;
    const int t = threadIdx.x;
    #pragma unroll 4
    for (int it = 0; it < 8; ++it) {
        const int qi = t + 256*it;                   // float4 idx 0..2047
        const int o8 = quarter*2 + (qi >> 10);       // row within group
        const float ga = gamma[g*8 + o8] * rs;
        const float be = beta[g*8 + o8];
        float4 yv = *(const float4*)&base[qi*4];
        float yn;
        yn = (yv.x - mu)*ga + be; yv.x = yn / (1.f + __expf(-yn));
        yn = (yv.y - mu)*ga + be; yv.y = yn / (1.f + __expf(-yn));
        yn = (yv.z - mu)*ga + be; yv.z = yn / (1.f + __expf(-yn));
        yn = (yv.w - mu)*ga + be; yv.w = yn / (1.f + __expf(-yn));
        *(float4*)&base[qi*4] = yv;
    }
}

// ---------------------------------------------------------------------------
// ws layout (float units):
// Q16=0(2M) | K16=2M | VT16=4M | HK=6M(4M) | LPART=10M | W16 | STATS
#define WS_Q16   0
#define WS_K16   2097152
#define WS_VT16  4194304
#define WS_HK    6291456
#define WS_LPART 10485760
#define WS_W16   10518528
#define WS_STATS 10649600

extern "C" void kernel_launch(void* const* d_in, const int* in_sizes, int n_in,
                              void* d_out, int out_size, void* d_ws, size_t ws_size,
                              hipStream_t stream)
{
    const float* x     = (const float*)d_in[0];
    const float* wq    = (const float*)d_in[1];
    const float* bq    = (const float*)d_in[2];
    const float* wk    = (const float*)d_in[3];
    const float* bk    = (const float*)d_in[4];
    const float* wv    = (const float*)d_in[5];
    const float* bv    = (const float*)d_in[6];
    const float* wo    = (const float*)d_in[7];
    const float* bo    = (const float*)d_in[8];
    const float* gamma = (const float*)d_in[9];
    const float* beta  = (const float*)d_in[10];

    float* out = (float*)d_out;
    float* ws  = (float*)d_ws;
    f16*   q16   = (f16*)(ws + WS_Q16);
    f16*   k16   = (f16*)(ws + WS_K16);
    u16*   vt16  = (u16*)(ws + WS_VT16);
    f16*   hk    = (f16*)(ws + WS_HK);
    float* lpart = ws + WS_LPART;
    f16*   w16   = (f16*)(ws + WS_W16);
    float* stats = ws + WS_STATS;

    prep_w_kernel<<<256, 256, 0, stream>>>(wq, wk, wv, wo, w16);

    qkv_kernel<<<dim3(NSP/32, BATCH), 256, 0, stream>>>(
        x, w16, bq, bk, bv, q16, k16, vt16);

    attn_kernel<<<512, 256, 0, stream>>>(q16, k16, vt16, hk, lpart);

    hipMemsetAsync(stats, 0, BATCH*NGRP*2*sizeof(float), stream);
    oproj_kernel<<<dim3(NSP/32, BATCH), 256, 0, stream>>>(
        hk, lpart, w16 + 3*65536, bo, x, out, stats);

    gn_swish_kernel<<<dim3(4, BATCH*NGRP), 256, 0, stream>>>(out, stats, gamma, beta);
}

// Round 16
// 232.205 us; speedup vs baseline: 1.4780x; 1.4780x over previous
//
#include <hip/hip_runtime.h>
#include <math.h>

#define BATCH 4
#define CH    256
#define NSP   4096          // 16*16*16
#define NGRP  32
#define EPS_GN 1e-5f
#define LOG2E 1.44269504088896f
#define M0    115.0f        // fixed softmax base (exp2 domain)

typedef _Float16 f16;
typedef f16 f16x8 __attribute__((ext_vector_type(8)));
typedef f16 f16x4 __attribute__((ext_vector_type(4)));
typedef short s16x8 __attribute__((ext_vector_type(8)));   // bf16 frags
typedef float f32x4 __attribute__((ext_vector_type(4)));
typedef unsigned short u16;

#define QK_MFMA(a,b,c) __builtin_amdgcn_mfma_f32_16x16x32_f16(a,b,c,0,0,0)
#define PV_MFMA(a,b,c) __builtin_amdgcn_mfma_f32_16x16x32_bf16(a,b,c,0,0,0)

__device__ __forceinline__ float fexp2(float x) {
    float r; asm("v_exp_f32 %0, %1" : "=v"(r) : "v"(x)); return r;
}
__device__ __forceinline__ unsigned cvtpk_bf16(float lo, float hi) {
    unsigned r; asm("v_cvt_pk_bf16_f32 %0, %1, %2" : "=v"(r) : "v"(lo), "v"(hi)); return r;
}
__device__ __forceinline__ u16 f2bf(float x) {      // RTNE float->bf16
    unsigned u = __float_as_uint(x);
    return (u16)((u + 0x7fffu + ((u >> 16) & 1u)) >> 16);
}
#define GLOAD_LDS(gsrc, ldst) __builtin_amdgcn_global_load_lds( \
    (const __attribute__((address_space(1))) unsigned int*)(gsrc), \
    (__attribute__((address_space(3))) unsigned int*)(ldst), 16, 0, 0)

// single per-tile barrier: P writes visible (lgkm) + K stage landed (vm)
#define BARRIER_ALL() do { \
    asm volatile("s_waitcnt vmcnt(0) lgkmcnt(0)" ::: "memory"); \
    __builtin_amdgcn_s_barrier(); \
    __builtin_amdgcn_sched_barrier(0); } while (0)

// ---------------------------------------------------------------------------
// prep: weights fp32 -> f16, layout [4][256][256] (wq*LOG2E, wk, wv, wo)
__global__ __launch_bounds__(256) void prep_w_kernel(
    const float* __restrict__ wq, const float* __restrict__ wk,
    const float* __restrict__ wv, const float* __restrict__ wo,
    f16* __restrict__ w16)
{
    const int i = (blockIdx.x * 256 + threadIdx.x) * 4;   // grid 256 -> 262144
    const float* src = (i < 65536) ? wq : (i < 131072) ? wk : (i < 196608) ? wv : wo;
    const float sc = (i < 65536) ? LOG2E : 1.f;           // fold softmax log2e into wq
    const float4 v = *(const float4*)&src[i & 65535];
    f16x4 o = { (f16)(v.x*sc), (f16)(v.y*sc), (f16)(v.z*sc), (f16)(v.w*sc) };
    *(f16x4*)&w16[i] = o;
}

// ---------------------------------------------------------------------------
// Fused QKV projection with in-LDS transpose: one block = 32 n x 256 o x 3 p.
// grid (N/32, B), block 256 (4 waves; wave w -> o slice w*64..+64).
__global__ __launch_bounds__(256, 2) void qkv_kernel(
    const float* __restrict__ x, const f16* __restrict__ w16,
    const float* __restrict__ bq, const float* __restrict__ bk,
    const float* __restrict__ bv,
    f16* __restrict__ q16, f16* __restrict__ k16, u16* __restrict__ vt16)
{
    __shared__ __align__(16) char Xls[16384];   // [32 n][256 c] f16, swz
    const int b = blockIdx.y, n0 = blockIdx.x * 32;
    const int t = threadIdx.x, w = t >> 6, lane = t & 63;
    const int m = lane & 15, q4 = lane >> 4;

    {   // transpose-stage: thread (n = t&31) loads 4 floats per c-quad, packs
        const float* xb = x + (size_t)b*CH*NSP + n0;
        const int n = t & 31;
        #pragma unroll
        for (int p8 = 0; p8 < 8; ++p8) {
            const int c = ((t >> 5) + p8*8) * 4;
            f16x4 o4;
            #pragma unroll
            for (int j = 0; j < 4; ++j)
                o4[j] = (f16)xb[(size_t)(c + j)*NSP + n];
            *(f16x4*)(Xls + n*512 + ((c*2) ^ ((n & 7) << 4))) = o4;
        }
    }
    __syncthreads();

    #pragma unroll 1
    for (int p = 0; p < 3; ++p) {
        const f16* __restrict__ W = w16 + p*65536;
        f32x4 acc[4][2] = {};
        #pragma unroll
        for (int kc = 0; kc < 8; ++kc) {
            s16x8 bf[2];   // raw 16B type for f16 data
            #pragma unroll
            for (int nf = 0; nf < 2; ++nf) {
                const int row = nf*16 + m;
                bf[nf] = *(const s16x8*)(Xls + row*512 +
                             ((kc*64 + q4*16) ^ ((row & 7) << 4)));
            }
            #pragma unroll
            for (int ar = 0; ar < 4; ++ar) {
                const f16x8 af = *(const f16x8*)(W + (size_t)(w*64 + ar*16 + m)*CH
                                                 + kc*32 + q4*8);
                acc[ar][0] = QK_MFMA(af, *(const f16x8*)&bf[0], acc[ar][0]);
                acc[ar][1] = QK_MFMA(af, *(const f16x8*)&bf[1], acc[ar][1]);
            }
        }
        if (p < 2) {
            const float* bias = (p == 0) ? bq : bk;
            const float bsc = (p == 0) ? LOG2E : 1.f;
            f16* out = (p == 0) ? q16 : k16;
            #pragma unroll
            for (int ar = 0; ar < 4; ++ar) {
                const int ob = w*64 + ar*16 + q4*4;
                const float4 bb = *(const float4*)&bias[ob];
                #pragma unroll
                for (int nf = 0; nf < 2; ++nf) {
                    const int n = n0 + nf*16 + m;
                    f16x4 o4 = { (f16)(acc[ar][nf][0] + bb.x*bsc),
                                 (f16)(acc[ar][nf][1] + bb.y*bsc),
                                 (f16)(acc[ar][nf][2] + bb.z*bsc),
                                 (f16)(acc[ar][nf][3] + bb.w*bsc) };
                    *(f16x4*)(out + ((size_t)(b*NSP) + n)*CH + ob) = o4;
                }
            }
        } else {
            #pragma unroll
            for (int ar = 0; ar < 4; ++ar) {
                const int ob = w*64 + ar*16 + q4*4;
                const float4 bb = *(const float4*)&bv[ob];
                const float br[4] = {bb.x, bb.y, bb.z, bb.w};
                #pragma unroll
                for (int nf = 0; nf < 2; ++nf) {
                    const int n = n0 + nf*16 + m;
                    #pragma unroll
                    for (int r = 0; r < 4; ++r)
                        vt16[((size_t)(b*CH) + ob + r)*NSP + n] =
                            f2bf(acc[ar][nf][r] + br[r]);
                }
            }
        }
    }
}

// ---------------------------------------------------------------------------
// Flash attention, single-barrier software pipeline — R14 retest at proper
// occupancy: RED overlaid onto Pls[0] after the final PV, so LDS = 81920 B
// EXACTLY (2x32K K-dbuf + 2x8K P-dbuf) -> 2 blocks/CU (R14's +512B RED
// pushed it to 1 block/CU and confounded the measurement).
// Per tile tt (one barrier-to-barrier body): stage K(tt+1) | load V(tt)->regs
// | PV(tt-1) from P-dbuf + prev V-regs | QK(tt) | exp -> write P(tt).
// grid 512 = (b,ks via bid&7) x qblk(bid>>3); block 256 (4 waves), 64 q-rows.
__global__ __launch_bounds__(256, 2) void attn_kernel(
    const f16* __restrict__ qg, const f16* __restrict__ kg,
    const u16* __restrict__ vtg, f16* __restrict__ hkg, float* __restrict__ lpart)
{
    __shared__ __align__(16) char Kls[2][32768];  // [64 keys][256c] f16, swz
    __shared__ __align__(16) char Pls[2][8192];   // [64 rows][64 keys] bf16, swz

    const int t = threadIdx.x, w = t >> 6, lane = t & 63;
    const int m = lane & 15, q4 = lane >> 4;
    const int swm = (m & 7) << 4;
    const int kh = w & 1, rh = w >> 1;
    const int bid = blockIdx.x;
    const int b   = (bid & 7) >> 1;     // XCD-pinned (b,ks): K/V half = 2MB/L2
    const int ks  = bid & 1;
    const int qn0 = (bid >> 3) * 64;
    const int k00 = ks * 2048;

    // Q frags (B-operand): wave's 32 rows x 256 ch = 64 VGPR
    f16x8 qa[2][8];
    #pragma unroll
    for (int rb2 = 0; rb2 < 2; ++rb2)
        #pragma unroll
        for (int kc = 0; kc < 8; ++kc)
            qa[rb2][kc] = *(const f16x8*)(qg + ((size_t)(b*NSP) + qn0 + rh*32
                                          + rb2*16 + m)*CH + kc*32 + q4*8);

    const char* kgb = (const char*)(kg + ((size_t)(b*NSP) + k00)*CH);
    const u16*  vb_ = vtg + ((size_t)(b*CH) + w*64 + m)*NSP + k00 + q4*8;

    auto stageK = [&](int buf, int tt) {
        const char* kgt = kgb + (size_t)tt * 64 * 512;
        char* dst = Kls[buf];
        #pragma unroll
        for (int i = 0; i < 8; ++i) {
            const int flat = i*4096 + t*16;
            const int key  = flat >> 9;
            const int off  = flat & 511;
            GLOAD_LDS(kgt + key*512 + (off ^ ((key & 7) << 4)), dst + flat);
        }
    };

    f32x4 acc[4][4] = {};
    float lsum[2] = {0.f, 0.f};

    s16x8 vbA[4][2], vbB[4][2];

    auto loadV = [&](int tt, s16x8 (&vb)[4][2]) {
        #pragma unroll
        for (int cf = 0; cf < 4; ++cf) {
            vb[cf][0] = *(const s16x8*)(vb_ + (size_t)(cf*16)*NSP + tt*64);
            vb[cf][1] = *(const s16x8*)(vb_ + (size_t)(cf*16)*NSP + tt*64 + 32);
        }
    };

    auto doQKexp = [&](const char* Kb, char* pbuf) {
        f32x4 s[2][2] = {};   // [kg key-block][rb2 row-block]
        __builtin_amdgcn_s_setprio(1);
        #pragma unroll
        for (int kc = 0; kc < 8; ++kc) {
            #pragma unroll
            for (int kg2 = 0; kg2 < 2; ++kg2) {
                const int key = kh*32 + kg2*16 + m;   // key&7 == m&7
                const f16x8 kb = *(const f16x8*)(Kb + key*512 +
                                     ((kc*64 + q4*16) ^ swm));
                s[kg2][0] = QK_MFMA(kb, qa[0][kc], s[kg2][0]);
                s[kg2][1] = QK_MFMA(kb, qa[1][kc], s[kg2][1]);
            }
        }
        __builtin_amdgcn_s_setprio(0);
        #pragma unroll
        for (int rb2 = 0; rb2 < 2; ++rb2) {
            const int prow = rh*32 + rb2*16 + m;      // prow&7 == m&7
            char* pr = pbuf + prow*128;
            #pragma unroll
            for (int kg2 = 0; kg2 < 2; ++kg2) {
                const float p0 = fexp2(s[kg2][rb2][0] - M0);
                const float p1 = fexp2(s[kg2][rb2][1] - M0);
                const float p2 = fexp2(s[kg2][rb2][2] - M0);
                const float p3 = fexp2(s[kg2][rb2][3] - M0);
                lsum[rb2] += (p0 + p1) + (p2 + p3);
                *(uint2*)(pr + ((kh*64 + kg2*32 + q4*8) ^ swm)) =
                    make_uint2(cvtpk_bf16(p0, p1), cvtpk_bf16(p2, p3));
            }
        }
    };

    auto doPV = [&](const char* pbuf, s16x8 (&vb)[4][2]) {
        __builtin_amdgcn_s_setprio(1);
        #pragma unroll
        for (int rb = 0; rb < 4; ++rb) {
            const char* pra = pbuf + (rb*16 + m)*128;
            const s16x8 pa0 = *(const s16x8*)(pra + ((q4*16) ^ swm));
            const s16x8 pa1 = *(const s16x8*)(pra + ((64 + q4*16) ^ swm));
            #pragma unroll
            for (int cf = 0; cf < 4; ++cf) {
                acc[rb][cf] = PV_MFMA(pa0, vb[cf][0], acc[rb][cf]);
                acc[rb][cf] = PV_MFMA(pa1, vb[cf][1], acc[rb][cf]);
            }
        }
        __builtin_amdgcn_s_setprio(0);
    };

    // ---- prologue: tile 0 ----
    stageK(0, 0);
    BARRIER_ALL();                       // K(0) landed
    stageK(1, 1);                        // K(1) in flight across tile-0 body
    loadV(0, vbA);
    doQKexp(Kls[0], Pls[0]);

    // ---- main loop: tt = 1..30, 2x unrolled (static vbA/vbB, rule #20) ----
    #pragma unroll 1
    for (int t2 = 0; t2 < 15; ++t2) {
        {   // tt = 2*t2+1 (odd): K[1], P write 1, PV reads P0/vbA
            const int tt = 2*t2 + 1;
            BARRIER_ALL();               // P(tt-1) visible; K(tt) landed
            stageK(0, tt + 1);
            loadV(tt, vbB);
            doPV(Pls[0], vbA);
            doQKexp(Kls[1], Pls[1]);
        }
        {   // tt = 2*t2+2 (even): K[0], P write 0, PV reads P1/vbB
            const int tt = 2*t2 + 2;
            BARRIER_ALL();
            stageK(1, tt + 1);
            loadV(tt, vbA);
            doPV(Pls[1], vbB);
            doQKexp(Kls[0], Pls[0]);
        }
    }
    // ---- tt = 31 (no further stage) ----
    BARRIER_ALL();
    loadV(31, vbB);
    doPV(Pls[0], vbA);
    doQKexp(Kls[1], Pls[1]);
    // ---- epilogue PV(31) ----
    BARRIER_ALL();
    doPV(Pls[1], vbB);

    // ---- epilogue: RED overlaid on Pls[0] (dead after last Pls[0] read) ----
    float (*RED)[2] = (float(*)[2])(&Pls[0][0]);
    #pragma unroll
    for (int rb2 = 0; rb2 < 2; ++rb2) {
        lsum[rb2] += __shfl_xor(lsum[rb2], 16);
        lsum[rb2] += __shfl_xor(lsum[rb2], 32);
    }
    __syncthreads();                     // all waves past Pls reads
    if (q4 == 0) {
        #pragma unroll
        for (int rb2 = 0; rb2 < 2; ++rb2)
            RED[rh*32 + rb2*16 + m][kh] = lsum[rb2];
    }
    __syncthreads();
    f16* hb = hkg + (size_t)ks*4194304 + ((size_t)(b*NSP) + qn0)*CH;
    #pragma unroll
    for (int rb = 0; rb < 4; ++rb)
        #pragma unroll
        for (int r = 0; r < 4; ++r) {
            const int row = rb*16 + q4*4 + r;
            const float linv = 1.f / (RED[row][0] + RED[row][1]);
            #pragma unroll
            for (int cf = 0; cf < 4; ++cf)
                hb[(size_t)row*CH + w*64 + cf*16 + m]
                    = (f16)(acc[rb][cf][r] * linv);
        }
    if (t < 64)
        lpart[ks*16384 + b*4096 + qn0 + t] = RED[t][0] + RED[t][1];
}

// ---------------------------------------------------------------------------
// Output projection with fused combine: one block = 32 n x 256 o.
// grid (N/32, B), block 256 (wave w -> o slice w*64..+64).
__global__ __launch_bounds__(256, 2) void oproj_kernel(
    const f16* __restrict__ hk, const float* __restrict__ lpart,
    const f16* __restrict__ wo16, const float* __restrict__ bo,
    const float* __restrict__ x, float* __restrict__ y, float* __restrict__ stats)
{
    __shared__ __align__(16) char Hls[16384];   // [32 n][256 c] f16, swz
    const int b = blockIdx.y, n0 = blockIdx.x * 32;
    const int t = threadIdx.x, w = t >> 6, lane = t & 63;
    const int m = lane & 15, q4 = lane >> 4;

    {   // stage combined h: 4 chunks of 16B per thread
        #pragma unroll
        for (int i = 0; i < 4; ++i) {
            const int flat = i*4096 + t*16;
            const int n = flat >> 9, off = flat & 511;
            const int nl = b*NSP + n0 + n;
            const float l0 = lpart[nl], l1 = lpart[16384 + nl];
            const float inv = 1.f / (l0 + l1);
            const float w0 = l0 * inv, w1 = l1 * inv;
            const f16x8 a = *(const f16x8*)(hk + (size_t)nl*CH + (off >> 1));
            const f16x8 c = *(const f16x8*)(hk + 4194304 + (size_t)nl*CH + (off >> 1));
            f16x8 o;
            #pragma unroll
            for (int j = 0; j < 8; ++j)
                o[j] = (f16)((float)a[j]*w0 + (float)c[j]*w1);
            *(f16x8*)(Hls + n*512 + (off ^ ((n & 7) << 4))) = o;
        }
    }
    __syncthreads();

    f32x4 acc[4][2] = {};
    #pragma unroll
    for (int kc = 0; kc < 8; ++kc) {
        s16x8 bf[2];
        #pragma unroll
        for (int nf = 0; nf < 2; ++nf) {
            const int row = nf*16 + m;
            bf[nf] = *(const s16x8*)(Hls + row*512 +
                         ((kc*64 + q4*16) ^ ((row & 7) << 4)));
        }
        #pragma unroll
        for (int ar = 0; ar < 4; ++ar) {
            const f16x8 af = *(const f16x8*)(wo16 + (size_t)(w*64 + ar*16 + m)*CH
                                             + kc*32 + q4*8);
            acc[ar][0] = QK_MFMA(af, *(const f16x8*)&bf[0], acc[ar][0]);
            acc[ar][1] = QK_MFMA(af, *(const f16x8*)&bf[1], acc[ar][1]);
        }
    }

    #pragma unroll
    for (int ar = 0; ar < 4; ++ar) {
        const int ob = w*64 + ar*16 + q4*4;
        const float4 bb = *(const float4*)&bo[ob];
        const float br[4] = {bb.x, bb.y, bb.z, bb.w};
        float s4 = 0.f, sq4 = 0.f;
        #pragma unroll
        for (int nf = 0; nf < 2; ++nf) {
            const int n = n0 + nf*16 + m;
            #pragma unroll
            for (int r = 0; r < 4; ++r) {
                const size_t idx = ((size_t)(b*CH + ob + r))*NSP + n;
                const float yv = acc[ar][nf][r] + br[r] + x[idx];
                y[idx] = yv;
                s4 += yv; sq4 += yv*yv;
            }
        }
        #pragma unroll
        for (int off = 1; off <= 16; off <<= 1) {
            s4  += __shfl_xor(s4, off);
            sq4 += __shfl_xor(sq4, off);
        }
        if ((lane & 31) == 0) {
            const int g = w*8 + ar*2 + (lane >> 5);
            atomicAdd(&stats[((size_t)(b*NGRP + g))*2 + 0], s4);
            atomicAdd(&stats[((size_t)(b*NGRP + g))*2 + 1], sq4);
        }
    }
}

// ---------------------------------------------------------------------------
// GroupNorm finalize + swish, in-place on y (= d_out).  grid (4, B*G).
__global__ __launch_bounds__(256) void gn_swish_kernel(
    float* __restrict__ y, const float* __restrict__ stats,
    const float* __restrict__ gamma, const float* __restrict__ beta)
{
    const int bg = blockIdx.y, quarter = blockIdx.x;
    const int b = bg >> 5, g = bg & 31;
    const float s  = stats[bg*2 + 0];
    const float sq = stats[bg*2 + 1];
    const float inv_n = 1.f / 32768.f;
    const float mu  = s * inv_n;
    const float var = sq * inv_n - mu*mu;
    const float rs  = rsqrtf(var + EPS_GN);
    float* __restrict__ base = y + ((size_t)b*CH + g*8)*NSP + quarter*8192;
    const int t = threadIdx.x;
    #pragma unroll 4
    for (int it = 0; it < 8; ++it) {
        const int qi = t + 256*it;                   // float4 idx 0..2047
        const int o8 = quarter*2 + (qi >> 10);       // row within group
        const float ga = gamma[g*8 + o8] * rs;
        const float be = beta[g*8 + o8];
        float4 yv = *(const float4*)&base[qi*4];
        float yn;
        yn = (yv.x - mu)*ga + be; yv.x = yn / (1.f + __expf(-yn));
        yn = (yv.y - mu)*ga + be; yv.y = yn / (1.f + __expf(-yn));
        yn = (yv.z - mu)*ga + be; yv.z = yn / (1.f + __expf(-yn));
        yn = (yv.w - mu)*ga + be; yv.w = yn / (1.f + __expf(-yn));
        *(float4*)&base[qi*4] = yv;
    }
}

// ---------------------------------------------------------------------------
// ws layout (float units):
// Q16=0(2M) | K16=2M | VT16=4M | HK=6M(4M) | LPART=10M | W16 | STATS
#define WS_Q16   0
#define WS_K16   2097152
#define WS_VT16  4194304
#define WS_HK    6291456
#define WS_LPART 10485760
#define WS_W16   10518528
#define WS_STATS 10649600

extern "C" void kernel_launch(void* const* d_in, const int* in_sizes, int n_in,
                              void* d_out, int out_size, void* d_ws, size_t ws_size,
                              hipStream_t stream)
{
    const float* x     = (const float*)d_in[0];
    const float* wq    = (const float*)d_in[1];
    const float* bq    = (const float*)d_in[2];
    const float* wk    = (const float*)d_in[3];
    const float* bk    = (const float*)d_in[4];
    const float* wv    = (const float*)d_in[5];
    const float* bv    = (const float*)d_in[6];
    const float* wo    = (const float*)d_in[7];
    const float* bo    = (const float*)d_in[8];
    const float* gamma = (const float*)d_in[9];
    const float* beta  = (const float*)d_in[10];

    float* out = (float*)d_out;
    float* ws  = (float*)d_ws;
    f16*   q16   = (f16*)(ws + WS_Q16);
    f16*   k16   = (f16*)(ws + WS_K16);
    u16*   vt16  = (u16*)(ws + WS_VT16);
    f16*   hk    = (f16*)(ws + WS_HK);
    float* lpart = ws + WS_LPART;
    f16*   w16   = (f16*)(ws + WS_W16);
    float* stats = ws + WS_STATS;

    prep_w_kernel<<<256, 256, 0, stream>>>(wq, wk, wv, wo, w16);

    qkv_kernel<<<dim3(NSP/32, BATCH), 256, 0, stream>>>(
        x, w16, bq, bk, bv, q16, k16, vt16);

    attn_kernel<<<512, 256, 0, stream>>>(q16, k16, vt16, hk, lpart);

    hipMemsetAsync(stats, 0, BATCH*NGRP*2*sizeof(float), stream);
    oproj_kernel<<<dim3(NSP/32, BATCH), 256, 0, stream>>>(
        hk, lpart, w16 + 3*65536, bo, x, out, stats);

    gn_swish_kernel<<<dim3(4, BATCH*NGRP), 256, 0, stream>>>(out, stats, gamma, beta);
}

// Round 17
// 170.562 us; speedup vs baseline: 2.0122x; 1.3614x over previous
//
#include <hip/hip_runtime.h>
#include <math.h>

#define BATCH 4
#define CH    256
#define NSP   4096          // 16*16*16
#define NGRP  32
#define EPS_GN 1e-5f
#define LOG2E 1.44269504088896f
#define M0    115.0f        // fixed softmax base (exp2 domain)

typedef _Float16 f16;
typedef f16 f16x8 __attribute__((ext_vector_type(8)));
typedef f16 f16x4 __attribute__((ext_vector_type(4)));
typedef short s16x8 __attribute__((ext_vector_type(8)));   // bf16 frags
typedef float f32x4 __attribute__((ext_vector_type(4)));
typedef unsigned short u16;

#define QK_MFMA(a,b,c) __builtin_amdgcn_mfma_f32_16x16x32_f16(a,b,c,0,0,0)
#define PV_MFMA(a,b,c) __builtin_amdgcn_mfma_f32_16x16x32_bf16(a,b,c,0,0,0)

__device__ __forceinline__ float fexp2(float x) {
    float r; asm("v_exp_f32 %0, %1" : "=v"(r) : "v"(x)); return r;
}
__device__ __forceinline__ unsigned cvtpk_bf16(float lo, float hi) {
    unsigned r; asm("v_cvt_pk_bf16_f32 %0, %1, %2" : "=v"(r) : "v"(lo), "v"(hi)); return r;
}
__device__ __forceinline__ u16 f2bf(float x) {      // RTNE float->bf16
    unsigned u = __float_as_uint(x);
    return (u16)((u + 0x7fffu + ((u >> 16) & 1u)) >> 16);
}
#define GLOAD_LDS(gsrc, ldst) __builtin_amdgcn_global_load_lds( \
    (const __attribute__((address_space(1))) unsigned int*)(gsrc), \
    (__attribute__((address_space(3))) unsigned int*)(ldst), 16, 0, 0)

#define LGKM_BARRIER() do { \
    asm volatile("s_waitcnt lgkmcnt(0)" ::: "memory"); \
    __builtin_amdgcn_s_barrier(); \
    __builtin_amdgcn_sched_barrier(0); } while (0)

#define VM_BARRIER() do { \
    asm volatile("s_waitcnt vmcnt(0)" ::: "memory"); \
    __builtin_amdgcn_s_barrier(); \
    __builtin_amdgcn_sched_barrier(0); } while (0)

// ---------------------------------------------------------------------------
// prep: weights fp32 -> f16, layout [4][256][256] (wq*LOG2E, wk, wv, wo)
__global__ __launch_bounds__(256) void prep_w_kernel(
    const float* __restrict__ wq, const float* __restrict__ wk,
    const float* __restrict__ wv, const float* __restrict__ wo,
    f16* __restrict__ w16)
{
    const int i = (blockIdx.x * 256 + threadIdx.x) * 4;   // grid 256 -> 262144
    const float* src = (i < 65536) ? wq : (i < 131072) ? wk : (i < 196608) ? wv : wo;
    const float sc = (i < 65536) ? LOG2E : 1.f;           // fold softmax log2e into wq
    const float4 v = *(const float4*)&src[i & 65535];
    f16x4 o = { (f16)(v.x*sc), (f16)(v.y*sc), (f16)(v.z*sc), (f16)(v.w*sc) };
    *(f16x4*)&w16[i] = o;
}

// ---------------------------------------------------------------------------
// Fused QKV projection with in-LDS transpose: one block = 32 n x 256 o x 3 p.
// Reads x [B][C][N] fp32 directly; transposes the 32n x 256c tile into LDS
// f16 (XOR-swizzled), then 3 GEMMs vs prescaled W.
// q,k: [B][N][C] f16 (q scaled via prescaled wq); v: [B][C][N] bf16.
// grid (N/32, B), block 256 (4 waves; wave w -> o slice w*64..+64).
__global__ __launch_bounds__(256, 2) void qkv_kernel(
    const float* __restrict__ x, const f16* __restrict__ w16,
    const float* __restrict__ bq, const float* __restrict__ bk,
    const float* __restrict__ bv,
    f16* __restrict__ q16, f16* __restrict__ k16, u16* __restrict__ vt16)
{
    __shared__ __align__(16) char Xls[16384];   // [32 n][256 c] f16, swz
    const int b = blockIdx.y, n0 = blockIdx.x * 32;
    const int t = threadIdx.x, w = t >> 6, lane = t & 63;
    const int m = lane & 15, q4 = lane >> 4;

    {   // transpose-stage: thread (n = t&31) loads 4 floats per c-quad, packs
        const float* xb = x + (size_t)b*CH*NSP + n0;
        const int n = t & 31;
        #pragma unroll
        for (int p8 = 0; p8 < 8; ++p8) {
            const int c = ((t >> 5) + p8*8) * 4;
            f16x4 o4;
            #pragma unroll
            for (int j = 0; j < 4; ++j)
                o4[j] = (f16)xb[(size_t)(c + j)*NSP + n];
            *(f16x4*)(Xls + n*512 + ((c*2) ^ ((n & 7) << 4))) = o4;
        }
    }
    __syncthreads();

    #pragma unroll 1
    for (int p = 0; p < 3; ++p) {
        const f16* __restrict__ W = w16 + p*65536;
        f32x4 acc[4][2] = {};
        #pragma unroll
        for (int kc = 0; kc < 8; ++kc) {
            s16x8 bf[2];   // raw 16B type for f16 data
            #pragma unroll
            for (int nf = 0; nf < 2; ++nf) {
                const int row = nf*16 + m;
                bf[nf] = *(const s16x8*)(Xls + row*512 +
                             ((kc*64 + q4*16) ^ ((row & 7) << 4)));
            }
            #pragma unroll
            for (int ar = 0; ar < 4; ++ar) {
                const f16x8 af = *(const f16x8*)(W + (size_t)(w*64 + ar*16 + m)*CH
                                                 + kc*32 + q4*8);
                acc[ar][0] = QK_MFMA(af, *(const f16x8*)&bf[0], acc[ar][0]);
                acc[ar][1] = QK_MFMA(af, *(const f16x8*)&bf[1], acc[ar][1]);
            }
        }
        if (p < 2) {
            const float* bias = (p == 0) ? bq : bk;
            const float bsc = (p == 0) ? LOG2E : 1.f;
            f16* out = (p == 0) ? q16 : k16;
            #pragma unroll
            for (int ar = 0; ar < 4; ++ar) {
                const int ob = w*64 + ar*16 + q4*4;
                const float4 bb = *(const float4*)&bias[ob];
                #pragma unroll
                for (int nf = 0; nf < 2; ++nf) {
                    const int n = n0 + nf*16 + m;
                    f16x4 o4 = { (f16)(acc[ar][nf][0] + bb.x*bsc),
                                 (f16)(acc[ar][nf][1] + bb.y*bsc),
                                 (f16)(acc[ar][nf][2] + bb.z*bsc),
                                 (f16)(acc[ar][nf][3] + bb.w*bsc) };
                    *(f16x4*)(out + ((size_t)(b*NSP) + n)*CH + ob) = o4;
                }
            }
        } else {
            #pragma unroll
            for (int ar = 0; ar < 4; ++ar) {
                const int ob = w*64 + ar*16 + q4*4;
                const float4 bb = *(const float4*)&bv[ob];
                const float br[4] = {bb.x, bb.y, bb.z, bb.w};
                #pragma unroll
                for (int nf = 0; nf < 2; ++nf) {
                    const int n = n0 + nf*16 + m;
                    #pragma unroll
                    for (int r = 0; r < 4; ++r)
                        vt16[((size_t)(b*CH) + ob + r)*NSP + n] =
                            f2bf(acc[ar][nf][r] + br[r]);
                }
            }
        }
    }
}

// ---------------------------------------------------------------------------
// Flash attention (best-measured config, R12): 2x2 QK wave ownership, K in
// shared LDS dbuf, V direct-to-reg issued before stage (counted vmcnt),
// uint2 P writes, fixed softmax base M0, setprio around MFMA clusters.
// q,k: [B][N][C] f16 (q pre-scaled); vt: [B][C][N] bf16.
// Outputs hk[2][B][N][C] f16 (per-half normalized) + lpart[2][B*N] f32.
// grid 512 = (b,ks via bid&7) x qblk(bid>>3); block 256 (4 waves), 64 q-rows.
__global__ __launch_bounds__(256, 2) void attn_kernel(
    const f16* __restrict__ qg, const f16* __restrict__ kg,
    const u16* __restrict__ vtg, f16* __restrict__ hkg, float* __restrict__ lpart)
{
    __shared__ __align__(16) char Kls[2][32768];  // [64 keys][256c] f16, swz
    __shared__ __align__(16) char Pls[8192];      // [64 rows][64 keys] bf16, swz
    __shared__ float RED[64][2];                  // per-row l, per key-half

    const int t = threadIdx.x, w = t >> 6, lane = t & 63;
    const int m = lane & 15, q4 = lane >> 4;
    const int swm = (m & 7) << 4;
    const int kh = w & 1, rh = w >> 1;
    const int bid = blockIdx.x;
    const int b   = (bid & 7) >> 1;     // XCD-pinned (b,ks): K/V half = 2MB/L2
    const int ks  = bid & 1;
    const int qn0 = (bid >> 3) * 64;
    const int k00 = ks * 2048;

    // Q frags (B-operand): wave's 32 rows x 256 ch = 64 VGPR
    f16x8 qa[2][8];
    #pragma unroll
    for (int rb2 = 0; rb2 < 2; ++rb2)
        #pragma unroll
        for (int kc = 0; kc < 8; ++kc)
            qa[rb2][kc] = *(const f16x8*)(qg + ((size_t)(b*NSP) + qn0 + rh*32
                                          + rb2*16 + m)*CH + kc*32 + q4*8);

    const char* kgb = (const char*)(kg + ((size_t)(b*NSP) + k00)*CH);
    const u16*  vb_ = vtg + ((size_t)(b*CH) + w*64 + m)*NSP + k00 + q4*8;

    // stage K tile: 32KB; linear LDS dest, pre-swizzled global source
    auto stageK = [&](int buf, int tt) {
        const char* kgt = kgb + (size_t)tt * 64 * 512;
        char* dst = Kls[buf];
        #pragma unroll
        for (int i = 0; i < 8; ++i) {
            const int flat = i*4096 + t*16;
            const int key  = flat >> 9;
            const int off  = flat & 511;
            GLOAD_LDS(kgt + key*512 + (off ^ ((key & 7) << 4)), dst + flat);
        }
    };

    f32x4 acc[4][4] = {};
    float lsum[2] = {0.f, 0.f};

    stageK(0, 0);

    #pragma unroll 1
    for (int tt = 0; tt < 32; ++tt) {
        const int buf = tt & 1;
        VM_BARRIER();                   // stage(tt) landed; P(tt-1) consumed by all

        // V fragments for tile tt FIRST: PV's wait is a counted vmcnt,
        // stage(tt+1) stays in flight across the whole tile.
        s16x8 vb[4][2];
        #pragma unroll
        for (int cf = 0; cf < 4; ++cf) {
            vb[cf][0] = *(const s16x8*)(vb_ + (size_t)(cf*16)*NSP + tt*64);
            vb[cf][1] = *(const s16x8*)(vb_ + (size_t)(cf*16)*NSP + tt*64 + 32);
        }
        __builtin_amdgcn_sched_barrier(0);   // pin V-issue before stage-issue
        if (tt < 31) stageK(buf ^ 1, tt + 1);

        // ---- QK^T: A = K (LDS, wave's 32 keys), B = Q (regs, wave's 32 rows)
        // each kb load feeds TWO MFMAs (row-blocks) -> half the LDS reads.
        const char* Kb = Kls[buf];
        f32x4 s[2][2] = {};   // [kg key-block][rb2 row-block]
        __builtin_amdgcn_s_setprio(1);
        #pragma unroll
        for (int kc = 0; kc < 8; ++kc) {
            #pragma unroll
            for (int kg = 0; kg < 2; ++kg) {
                const int key = kh*32 + kg*16 + m;   // key&7 == m&7
                const f16x8 kb = *(const f16x8*)(Kb + key*512 +
                                     ((kc*64 + q4*16) ^ swm));
                s[kg][0] = QK_MFMA(kb, qa[0][kc], s[kg][0]);
                s[kg][1] = QK_MFMA(kb, qa[1][kc], s[kg][1]);
            }
        }
        __builtin_amdgcn_s_setprio(0);

        // ---- exp (fixed base) + P -> LDS: uint2 per (rb2, kg) ----
        #pragma unroll
        for (int rb2 = 0; rb2 < 2; ++rb2) {
            const int prow = rh*32 + rb2*16 + m;     // prow&7 == m&7
            char* pr = Pls + prow*128;
            #pragma unroll
            for (int kg = 0; kg < 2; ++kg) {
                const float p0 = fexp2(s[kg][rb2][0] - M0);
                const float p1 = fexp2(s[kg][rb2][1] - M0);
                const float p2 = fexp2(s[kg][rb2][2] - M0);
                const float p3 = fexp2(s[kg][rb2][3] - M0);
                lsum[rb2] += (p0 + p1) + (p2 + p3);
                *(uint2*)(pr + ((kh*64 + kg*32 + q4*8) ^ swm)) =
                    make_uint2(cvtpk_bf16(p0, p1), cvtpk_bf16(p2, p3));
            }
        }
        LGKM_BARRIER();                 // P visible; stage loads stay in flight

        // ---- PV: channels w*64+cf*16+m, rows rb*16+q4*4+r ----
        __builtin_amdgcn_s_setprio(1);
        #pragma unroll
        for (int rb = 0; rb < 4; ++rb) {
            const char* pra = Pls + (rb*16 + m)*128;
            const s16x8 pa0 = *(const s16x8*)(pra + ((q4*16) ^ swm));
            const s16x8 pa1 = *(const s16x8*)(pra + ((64 + q4*16) ^ swm));
            #pragma unroll
            for (int cf = 0; cf < 4; ++cf) {
                acc[rb][cf] = PV_MFMA(pa0, vb[cf][0], acc[rb][cf]);
                acc[rb][cf] = PV_MFMA(pa1, vb[cf][1], acc[rb][cf]);
            }
        }
        __builtin_amdgcn_s_setprio(0);
        // next iteration's VM_BARRIER is the WAR fence for Pls
    }

    // ---- epilogue: per-row l = sum over both key-half waves ----
    #pragma unroll
    for (int rb2 = 0; rb2 < 2; ++rb2) {
        lsum[rb2] += __shfl_xor(lsum[rb2], 16);
        lsum[rb2] += __shfl_xor(lsum[rb2], 32);
    }
    if (q4 == 0) {
        #pragma unroll
        for (int rb2 = 0; rb2 < 2; ++rb2)
            RED[rh*32 + rb2*16 + m][kh] = lsum[rb2];
    }
    __syncthreads();
    f16* hb = hkg + (size_t)ks*4194304 + ((size_t)(b*NSP) + qn0)*CH;
    #pragma unroll
    for (int rb = 0; rb < 4; ++rb)
        #pragma unroll
        for (int r = 0; r < 4; ++r) {
            const int row = rb*16 + q4*4 + r;
            const float linv = 1.f / (RED[row][0] + RED[row][1]);
            #pragma unroll
            for (int cf = 0; cf < 4; ++cf)
                hb[(size_t)row*CH + w*64 + cf*16 + m]
                    = (f16)(acc[rb][cf][r] * linv);
        }
    if (t < 64)
        lpart[ks*16384 + b*4096 + qn0 + t] = RED[t][0] + RED[t][1];
}

// ---------------------------------------------------------------------------
// Output projection with fused combine: one block = 32 n x 256 o.
// Stages h = (hk0*l0 + hk1*l1)/(l0+l1) into LDS, then GEMM vs wo16,
// adds residual x, writes y fp32 (= d_out), accumulates group stats.
// grid (N/32, B), block 256 (wave w -> o slice w*64..+64).
__global__ __launch_bounds__(256, 2) void oproj_kernel(
    const f16* __restrict__ hk, const float* __restrict__ lpart,
    const f16* __restrict__ wo16, const float* __restrict__ bo,
    const float* __restrict__ x, float* __restrict__ y, float* __restrict__ stats)
{
    __shared__ __align__(16) char Hls[16384];   // [32 n][256 c] f16, swz
    const int b = blockIdx.y, n0 = blockIdx.x * 32;
    const int t = threadIdx.x, w = t >> 6, lane = t & 63;
    const int m = lane & 15, q4 = lane >> 4;

    {   // stage combined h: 4 chunks of 16B per thread
        #pragma unroll
        for (int i = 0; i < 4; ++i) {
            const int flat = i*4096 + t*16;
            const int n = flat >> 9, off = flat & 511;
            const int nl = b*NSP + n0 + n;
            const float l0 = lpart[nl], l1 = lpart[16384 + nl];
            const float inv = 1.f / (l0 + l1);
            const float w0 = l0 * inv, w1 = l1 * inv;
            const f16x8 a = *(const f16x8*)(hk + (size_t)nl*CH + (off >> 1));
            const f16x8 c = *(const f16x8*)(hk + 4194304 + (size_t)nl*CH + (off >> 1));
            f16x8 o;
            #pragma unroll
            for (int j = 0; j < 8; ++j)
                o[j] = (f16)((float)a[j]*w0 + (float)c[j]*w1);
            *(f16x8*)(Hls + n*512 + (off ^ ((n & 7) << 4))) = o;
        }
    }
    __syncthreads();

    f32x4 acc[4][2] = {};
    #pragma unroll
    for (int kc = 0; kc < 8; ++kc) {
        s16x8 bf[2];
        #pragma unroll
        for (int nf = 0; nf < 2; ++nf) {
            const int row = nf*16 + m;
            bf[nf] = *(const s16x8*)(Hls + row*512 +
                         ((kc*64 + q4*16) ^ ((row & 7) << 4)));
        }
        #pragma unroll
        for (int ar = 0; ar < 4; ++ar) {
            const f16x8 af = *(const f16x8*)(wo16 + (size_t)(w*64 + ar*16 + m)*CH
                                             + kc*32 + q4*8);
            acc[ar][0] = QK_MFMA(af, *(const f16x8*)&bf[0], acc[ar][0]);
            acc[ar][1] = QK_MFMA(af, *(const f16x8*)&bf[1], acc[ar][1]);
        }
    }

    #pragma unroll
    for (int ar = 0; ar < 4; ++ar) {
        const int ob = w*64 + ar*16 + q4*4;
        const float4 bb = *(const float4*)&bo[ob];
        const float br[4] = {bb.x, bb.y, bb.z, bb.w};
        float s4 = 0.f, sq4 = 0.f;
        #pragma unroll
        for (int nf = 0; nf < 2; ++nf) {
            const int n = n0 + nf*16 + m;
            #pragma unroll
            for (int r = 0; r < 4; ++r) {
                const size_t idx = ((size_t)(b*CH + ob + r))*NSP + n;
                const float yv = acc[ar][nf][r] + br[r] + x[idx];
                y[idx] = yv;
                s4 += yv; sq4 += yv*yv;
            }
        }
        #pragma unroll
        for (int off = 1; off <= 16; off <<= 1) {
            s4  += __shfl_xor(s4, off);
            sq4 += __shfl_xor(sq4, off);
        }
        if ((lane & 31) == 0) {
            const int g = w*8 + ar*2 + (lane >> 5);
            atomicAdd(&stats[((size_t)(b*NGRP + g))*2 + 0], s4);
            atomicAdd(&stats[((size_t)(b*NGRP + g))*2 + 1], sq4);
        }
    }
}

// ---------------------------------------------------------------------------
// GroupNorm finalize + swish, in-place on y (= d_out).  grid (4, B*G).
__global__ __launch_bounds__(256) void gn_swish_kernel(
    float* __restrict__ y, const float* __restrict__ stats,
    const float* __restrict__ gamma, const float* __restrict__ beta)
{
    const int bg = blockIdx.y, quarter = blockIdx.x;
    const int b = bg >> 5, g = bg & 31;
    const float s  = stats[bg*2 + 0];
    const float sq = stats[bg*2 + 1];
    const float inv_n = 1.f / 32768.f;
    const float mu  = s * inv_n;
    const float var = sq * inv_n - mu*mu;
    const float rs  = rsqrtf(var + EPS_GN);
    float* __restrict__ base = y + ((size_t)b*CH + g*8)*NSP + quarter*8192;
    const int t = threadIdx.x;
    #pragma unroll 4
    for (int it = 0; it < 8; ++it) {
        const int qi = t + 256*it;                   // float4 idx 0..2047
        const int o8 = quarter*2 + (qi >> 10);       // row within group
        const float ga = gamma[g*8 + o8] * rs;
        const float be = beta[g*8 + o8];
        float4 yv = *(const float4*)&base[qi*4];
        float yn;
        yn = (yv.x - mu)*ga + be; yv.x = yn / (1.f + __expf(-yn));
        yn = (yv.y - mu)*ga + be; yv.y = yn / (1.f + __expf(-yn));
        yn = (yv.z - mu)*ga + be; yv.z = yn / (1.f + __expf(-yn));
        yn = (yv.w - mu)*ga + be; yv.w = yn / (1.f + __expf(-yn));
        *(float4*)&base[qi*4] = yv;
    }
}

// ---------------------------------------------------------------------------
// ws layout (float units):
// Q16=0(2M) | K16=2M | VT16=4M | HK=6M(4M) | LPART=10M | W16 | STATS
#define WS_Q16   0
#define WS_K16   2097152
#define WS_VT16  4194304
#define WS_HK    6291456
#define WS_LPART 10485760
#define WS_W16   10518528
#define WS_STATS 10649600

extern "C" void kernel_launch(void* const* d_in, const int* in_sizes, int n_in,
                              void* d_out, int out_size, void* d_ws, size_t ws_size,
                              hipStream_t stream)
{
    const float* x     = (const float*)d_in[0];
    const float* wq    = (const float*)d_in[1];
    const float* bq    = (const float*)d_in[2];
    const float* wk    = (const float*)d_in[3];
    const float* bk    = (const float*)d_in[4];
    const float* wv    = (const float*)d_in[5];
    const float* bv    = (const float*)d_in[6];
    const float* wo    = (const float*)d_in[7];
    const float* bo    = (const float*)d_in[8];
    const float* gamma = (const float*)d_in[9];
    const float* beta  = (const float*)d_in[10];

    float* out = (float*)d_out;
    float* ws  = (float*)d_ws;
    f16*   q16   = (f16*)(ws + WS_Q16);
    f16*   k16   = (f16*)(ws + WS_K16);
    u16*   vt16  = (u16*)(ws + WS_VT16);
    f16*   hk    = (f16*)(ws + WS_HK);
    float* lpart = ws + WS_LPART;
    f16*   w16   = (f16*)(ws + WS_W16);
    float* stats = ws + WS_STATS;

    prep_w_kernel<<<256, 256, 0, stream>>>(wq, wk, wv, wo, w16);

    qkv_kernel<<<dim3(NSP/32, BATCH), 256, 0, stream>>>(
        x, w16, bq, bk, bv, q16, k16, vt16);

    attn_kernel<<<512, 256, 0, stream>>>(q16, k16, vt16, hk, lpart);

    hipMemsetAsync(stats, 0, BATCH*NGRP*2*sizeof(float), stream);
    oproj_kernel<<<dim3(NSP/32, BATCH), 256, 0, stream>>>(
        hk, lpart, w16 + 3*65536, bo, x, out, stats);

    gn_swish_kernel<<<dim3(4, BATCH*NGRP), 256, 0, stream>>>(out, stats, gamma, beta);
}